// Round 13
// baseline (124.998 us; speedup 1.0000x reference)
//
#include <hip/hip_runtime.h>
#include <hip/hip_bf16.h>
#include <stdint.h>

#define SDIM 2048
#define BDIM 8
#define FDIM 512
constexpr float ALPHA = 0.2f;

typedef __attribute__((ext_vector_type(8))) short bf16x8;
typedef __attribute__((ext_vector_type(4))) float f32x4;

__device__ __forceinline__ unsigned short f2bf(float x) {
  __hip_bfloat16 h = __float2bfloat16(x);
  return *reinterpret_cast<unsigned short*>(&h);
}

__device__ __forceinline__ void gload_lds16(const void* g, void* l) {
  __builtin_amdgcn_global_load_lds(
      (const __attribute__((address_space(1))) unsigned int*)(uintptr_t)g,
      (__attribute__((address_space(3))) unsigned int*)(uintptr_t)l,
      16, 0, 0);
}

// ---------------- K0: wa1/wa2 = W @ a halves (fp32), WT = bf16(W^T) ----------------
__global__ void k0_prep(const float* __restrict__ W, const float* __restrict__ a,
                        float* __restrict__ wa, __hip_bfloat16* __restrict__ WT) {
  int i = blockIdx.x;            // 512 rows of W
  int lane = threadIdx.x;        // 64
  float s1 = 0.f, s2 = 0.f;
  for (int o = lane; o < FDIM; o += 64) {
    float w = W[i * FDIM + o];
    s1 += w * a[o];
    s2 += w * a[FDIM + o];
    WT[o * FDIM + i] = __float2bfloat16(w);
  }
  #pragma unroll
  for (int off = 32; off > 0; off >>= 1) {
    s1 += __shfl_down(s1, off);
    s2 += __shfl_down(s2, off);
  }
  if (lane == 0) { wa[i] = s1; wa[FDIM + i] = s2; }
}

// ---------------- K1: per-row Wh1/Wh2 (fp32) + H -> bf16 ----------------
__global__ __launch_bounds__(256) void k1_rows(const float* __restrict__ H,
                                               const float* __restrict__ wa,
                                               float* __restrict__ Wh1, float* __restrict__ Wh2,
                                               __hip_bfloat16* __restrict__ Hb) {
  int wid = threadIdx.x >> 6, lane = threadIdx.x & 63;
  long r = (long)blockIdx.x * 4 + wid;          // 0..16383
  const float* hr = H + r * FDIM;
  float4 v0 = ((const float4*)hr)[lane];
  float4 v1 = ((const float4*)hr)[lane + 64];
  float4 wa10 = ((const float4*)wa)[lane];
  float4 wa11 = ((const float4*)wa)[lane + 64];
  float4 wa20 = ((const float4*)(wa + FDIM))[lane];
  float4 wa21 = ((const float4*)(wa + FDIM))[lane + 64];
  float s1 = v0.x*wa10.x + v0.y*wa10.y + v0.z*wa10.z + v0.w*wa10.w
           + v1.x*wa11.x + v1.y*wa11.y + v1.z*wa11.z + v1.w*wa11.w;
  float s2 = v0.x*wa20.x + v0.y*wa20.y + v0.z*wa20.z + v0.w*wa20.w
           + v1.x*wa21.x + v1.y*wa21.y + v1.z*wa21.z + v1.w*wa21.w;
  ushort4 u0 = { f2bf(v0.x), f2bf(v0.y), f2bf(v0.z), f2bf(v0.w) };
  ushort4 u1 = { f2bf(v1.x), f2bf(v1.y), f2bf(v1.z), f2bf(v1.w) };
  ushort4* hb = (ushort4*)(Hb + r * FDIM);
  hb[lane] = u0;
  hb[lane + 64] = u1;
  #pragma unroll
  for (int off = 32; off > 0; off >>= 1) {
    s1 += __shfl_down(s1, off);
    s2 += __shfl_down(s2, off);
  }
  if (lane == 0) { Wh1[r] = s1; Wh2[r] = s2; }
}

// ---------------- K2: column sums Z[b,t] AND P = bf16(masked exp) ----------------
__global__ __launch_bounds__(256) void k2_z(const float* __restrict__ adj,
                                            const float* __restrict__ Wh1,
                                            const float* __restrict__ Wh2,
                                            float* __restrict__ Zp,
                                            __hip_bfloat16* __restrict__ P) {
  int t = blockIdx.x * 256 + threadIdx.x;  // grid.x = 8
  int b = blockIdx.y;                      // 8
  int c = blockIdx.z;                      // 32 chunks of 64 s each
  float w2 = Wh2[b * SDIM + t];
  const float* arow = adj + ((long)b * SDIM + c * 64) * SDIM + t;
  const float* w1p = Wh1 + b * SDIM + c * 64;
  __hip_bfloat16* prow = P + ((long)b * SDIM + c * 64) * SDIM + t;
  float z = 0.f;
  #pragma unroll 8
  for (int s = 0; s < 64; ++s) {
    float av = arow[(long)s * SDIM];
    float e = w1p[s] + w2;
    e = fmaxf(e, ALPHA * e);
    float p = (av > 0.5f) ? __expf(e) : 0.f;
    z += p;
    prow[(long)s * SDIM] = __float2bfloat16(p);
  }
  Zp[(b * 32 + c) * SDIM + t] = z;
}

// ---------------- K2b: rZ = 1/sum(partials) ----------------
__global__ void k2b_rz(const float* __restrict__ Zp, float* __restrict__ rZ) {
  int idx = blockIdx.x * 256 + threadIdx.x;  // 16384
  int b = idx >> 11, t = idx & 2047;
  float z = 0.f;
  #pragma unroll
  for (int c = 0; c < 32; ++c) z += Zp[(b * 32 + c) * SDIM + t];
  rZ[idx] = 1.0f / z;
}

// ---------------- K3: V'^T[b][o][t] = bf16( (W^T @ H_b^T)[o][t] * rZ[b,t] ) ----------------
__global__ __launch_bounds__(256) void k3_gemm(const __hip_bfloat16* __restrict__ WTm,
                                               const __hip_bfloat16* __restrict__ Hb,
                                               const float* __restrict__ rZ,
                                               __hip_bfloat16* __restrict__ VT) {
  __shared__ __align__(16) __hip_bfloat16 Asm[2][128 * 32];
  __shared__ __align__(16) __hip_bfloat16 Bsm[2][128 * 32];
  const int o0 = blockIdx.x * 128;
  const int t0 = blockIdx.y * 128;
  const int b = blockIdx.z;
  const int tid = threadIdx.x;
  const int w = tid >> 6, lane = tid & 63;
  const int wm = w >> 1, wn = w & 1;
  const int fr = lane & 15, fq = lane >> 4;
  const int lr = lane >> 2, lb = (lane & 3) * 16;

  const __hip_bfloat16* Abase = WTm + (long)o0 * FDIM;
  const __hip_bfloat16* Bbase = Hb + ((long)b * SDIM + t0) * FDIM;

  f32x4 acc[4][4] = {};

  auto stage = [&](int kk, int buf) {
    #pragma unroll
    for (int g = 0; g < 2; ++g) {
      int rbase = g * 64 + w * 16;
      int row = rbase + lr;
      gload_lds16((const char*)(Abase + (long)row * FDIM + kk * 32) + lb,
                  (char*)&Asm[buf][0] + rbase * 64);
      gload_lds16((const char*)(Bbase + (long)row * FDIM + kk * 32) + lb,
                  (char*)&Bsm[buf][0] + rbase * 64);
    }
  };

  stage(0, 0);
  __syncthreads();
  for (int kk = 0; kk < 16; ++kk) {
    int cur = kk & 1;
    if (kk < 15) stage(kk + 1, cur ^ 1);
    bf16x8 af[4], bf_[4];
    #pragma unroll
    for (int mf = 0; mf < 4; ++mf)
      af[mf] = *(const bf16x8*)((const char*)&Asm[cur][0] + (wm * 64 + mf * 16 + fr) * 64 + fq * 16);
    #pragma unroll
    for (int nf = 0; nf < 4; ++nf)
      bf_[nf] = *(const bf16x8*)((const char*)&Bsm[cur][0] + (wn * 64 + nf * 16 + fr) * 64 + fq * 16);
    #pragma unroll
    for (int mf = 0; mf < 4; ++mf)
      #pragma unroll
      for (int nf = 0; nf < 4; ++nf)
        acc[mf][nf] = __builtin_amdgcn_mfma_f32_16x16x32_bf16(af[mf], bf_[nf], acc[mf][nf], 0, 0, 0);
    __syncthreads();
  }

  #pragma unroll
  for (int nf = 0; nf < 4; ++nf) {
    int t = t0 + wn * 64 + nf * 16 + fr;
    float rz = rZ[b * SDIM + t];
    #pragma unroll
    for (int mf = 0; mf < 4; ++mf) {
      #pragma unroll
      for (int r = 0; r < 4; ++r) {
        int o = o0 + wm * 64 + mf * 16 + fq * 4 + r;
        VT[((long)(b * FDIM + o)) * SDIM + t] = __float2bfloat16(acc[mf][nf][r] * rz);
      }
    }
  }
}

// ---------------- K4 v13: out = elu( P @ V' ), pure staged GEMM ----------------
// P precomputed by K2 (bf16, L3-resident). Per phase: 5 DMA (V 4 + P 1, both
// 1 phase ahead), 8 ds_reads (granule-XOR swizzled, 0-conflict), 16 MFMA,
// one barrier. No build VALU, no adjacency, no w2l.
__global__ __launch_bounds__(256, 2) void k4_pv(const __hip_bfloat16* __restrict__ P,
                                                const __hip_bfloat16* __restrict__ VT,
                                                float* __restrict__ out) {
  __shared__ __align__(16) __hip_bfloat16 Vsm[2][256 * 32];  // 32 KB
  __shared__ __align__(16) __hip_bfloat16 Psm[2][64 * 32];   // 8 KB
  const int b  = blockIdx.x;        // 8  (linear id % 8 == b -> XCD pinning)
  const int s0 = blockIdx.y * 64;   // 32
  const int ob = blockIdx.z * 256;  // 2
  const int tid = threadIdx.x;
  const int w = tid >> 6, lane = tid & 63;
  const int fr = lane & 15, fq = lane >> 4;
  const int srow = lane >> 2;                        // staging: row within 16-row block
  const int sgam = (lane & 3) ^ ((lane >> 2) & 3);   // staging: XOR'd source granule

  const char* vtG = (const char*)(VT + ((long)(b * FDIM + ob)) * SDIM);
  const char* pG  = (const char*)(P + ((long)(b * SDIM + s0)) * SDIM);

  f32x4 acc[4][4] = {};

  auto stageV = [&](int p, int buf) {
    #pragma unroll
    for (int g = 0; g < 4; ++g) {
      int row = w * 64 + g * 16 + srow;
      gload_lds16(vtG + ((long)row * SDIM + p * 32 + sgam * 8) * 2,
                  (char*)&Vsm[buf][0] + w * 4096 + g * 1024);
    }
  };
  auto stageP = [&](int p, int buf) {
    int row = w * 16 + srow;
    gload_lds16(pG + ((long)row * SDIM + p * 32 + sgam * 8) * 2,
                (char*)&Psm[buf][0] + w * 1024);
  };

  // prologue
  stageV(0, 0);
  stageP(0, 0);
  asm volatile("s_waitcnt vmcnt(0)" ::: "memory");
  __builtin_amdgcn_sched_barrier(0);
  __builtin_amdgcn_s_barrier();

  for (int p = 0; p < 64; ++p) {
    const int cur = p & 1;
    if (p < 63) { stageV(p + 1, cur ^ 1); stageP(p + 1, cur ^ 1); }
    __builtin_amdgcn_sched_barrier(0);        // stages issue at phase top

    bf16x8 pa[4], vb[4];
    #pragma unroll
    for (int mf = 0; mf < 4; ++mf)
      pa[mf] = *(const bf16x8*)((const char*)&Psm[cur][0] + mf * 1024
                                + fr * 64 + (fq ^ (fr & 3)) * 16);
    #pragma unroll
    for (int nf = 0; nf < 4; ++nf)
      vb[nf] = *(const bf16x8*)((const char*)&Vsm[cur][0] + w * 4096 + nf * 1024
                                + fr * 64 + (fq ^ (fr & 3)) * 16);
    __builtin_amdgcn_s_setprio(1);
    #pragma unroll
    for (int mf = 0; mf < 4; ++mf)
      #pragma unroll
      for (int nf = 0; nf < 4; ++nf)
        acc[mf][nf] = __builtin_amdgcn_mfma_f32_16x16x32_bf16(pa[mf], vb[nf], acc[mf][nf], 0, 0, 0);
    __builtin_amdgcn_s_setprio(0);

    asm volatile("s_waitcnt vmcnt(0) lgkmcnt(0)" ::: "memory");
    __builtin_amdgcn_sched_barrier(0);
    __builtin_amdgcn_s_barrier();
  }

  // epilogue: ELU + store
  float* orow = out + ((long)b * SDIM + s0) * FDIM + ob + w * 64;
  #pragma unroll
  for (int mf = 0; mf < 4; ++mf) {
    #pragma unroll
    for (int nf = 0; nf < 4; ++nf) {
      #pragma unroll
      for (int r = 0; r < 4; ++r) {
        int s = mf * 16 + fq * 4 + r;
        int o = nf * 16 + fr;
        float x = acc[mf][nf][r];
        x = x > 0.f ? x : (__expf(x) - 1.f);
        orow[(long)s * FDIM + o] = x;
      }
    }
  }
}

extern "C" void kernel_launch(void* const* d_in, const int* in_sizes, int n_in,
                              void* d_out, int out_size, void* d_ws, size_t ws_size,
                              hipStream_t stream) {
  const float* H   = (const float*)d_in[0];   // [8,2048,512]
  const float* adj = (const float*)d_in[1];   // [8,2048,2048]
  const float* W   = (const float*)d_in[2];   // [512,512]
  const float* a   = (const float*)d_in[3];   // [1024,1]
  float* out = (float*)d_out;
  char* ws = (char*)d_ws;

  __hip_bfloat16* VT  = (__hip_bfloat16*)(ws + 0);         // 16 MB  [8][512][2048]
  __hip_bfloat16* Hb  = (__hip_bfloat16*)(ws + 16777216);  // 16 MB  [16384][512]
  __hip_bfloat16* WT  = (__hip_bfloat16*)(ws + 33554432);  // 512 KB [512][512]
  float* wa  = (float*)(ws + 34078720);                    // 4 KB
  float* Wh1 = (float*)(ws + 34082816);                    // 64 KB
  float* Wh2 = (float*)(ws + 34148352);                    // 64 KB
  float* rZ  = (float*)(ws + 34213888);                    // 64 KB
  float* Zp  = (float*)(ws + 34279424);                    // 2 MB
  __hip_bfloat16* P = (__hip_bfloat16*)(ws + 37748736);    // 64 MB  [8][2048][2048]

  hipLaunchKernelGGL(k0_prep, dim3(512), dim3(64), 0, stream, W, a, wa, WT);
  hipLaunchKernelGGL(k1_rows, dim3(4096), dim3(256), 0, stream, H, wa, Wh1, Wh2, Hb);
  hipLaunchKernelGGL(k2_z, dim3(8, 8, 32), dim3(256), 0, stream, adj, Wh1, Wh2, Zp, P);
  hipLaunchKernelGGL(k2b_rz, dim3(64), dim3(256), 0, stream, Zp, rZ);
  hipLaunchKernelGGL(k3_gemm, dim3(4, 16, 8), dim3(256), 0, stream, WT, Hb, rZ, VT);
  hipLaunchKernelGGL(k4_pv, dim3(8, 32, 2), dim3(256), 0, stream, P, VT, out);
}

// Round 14
// 123.803 us; speedup vs baseline: 1.0097x; 1.0097x over previous
//
#include <hip/hip_runtime.h>
#include <hip/hip_bf16.h>
#include <stdint.h>

#define SDIM 2048
#define BDIM 8
#define FDIM 512
constexpr float ALPHA = 0.2f;

typedef __attribute__((ext_vector_type(8))) short bf16x8;
typedef __attribute__((ext_vector_type(4))) float f32x4;

__device__ __forceinline__ unsigned short f2bf(float x) {
  __hip_bfloat16 h = __float2bfloat16(x);
  return *reinterpret_cast<unsigned short*>(&h);
}

__device__ __forceinline__ void gload_lds16(const void* g, void* l) {
  __builtin_amdgcn_global_load_lds(
      (const __attribute__((address_space(1))) unsigned int*)(uintptr_t)g,
      (__attribute__((address_space(3))) unsigned int*)(uintptr_t)l,
      16, 0, 0);
}

// ---------------- K0: wa1/wa2 = W @ a halves (fp32), WT = bf16(W^T) ----------------
__global__ void k0_prep(const float* __restrict__ W, const float* __restrict__ a,
                        float* __restrict__ wa, __hip_bfloat16* __restrict__ WT) {
  int i = blockIdx.x;            // 512 rows of W
  int lane = threadIdx.x;        // 64
  float s1 = 0.f, s2 = 0.f;
  for (int o = lane; o < FDIM; o += 64) {
    float w = W[i * FDIM + o];
    s1 += w * a[o];
    s2 += w * a[FDIM + o];
    WT[o * FDIM + i] = __float2bfloat16(w);
  }
  #pragma unroll
  for (int off = 32; off > 0; off >>= 1) {
    s1 += __shfl_down(s1, off);
    s2 += __shfl_down(s2, off);
  }
  if (lane == 0) { wa[i] = s1; wa[FDIM + i] = s2; }
}

// ---------------- K1: per-row Wh1/Wh2 (fp32) + H -> bf16 ----------------
__global__ __launch_bounds__(256) void k1_rows(const float* __restrict__ H,
                                               const float* __restrict__ wa,
                                               float* __restrict__ Wh1, float* __restrict__ Wh2,
                                               __hip_bfloat16* __restrict__ Hb) {
  int wid = threadIdx.x >> 6, lane = threadIdx.x & 63;
  long r = (long)blockIdx.x * 4 + wid;          // 0..16383
  const float* hr = H + r * FDIM;
  float4 v0 = ((const float4*)hr)[lane];
  float4 v1 = ((const float4*)hr)[lane + 64];
  float4 wa10 = ((const float4*)wa)[lane];
  float4 wa11 = ((const float4*)wa)[lane + 64];
  float4 wa20 = ((const float4*)(wa + FDIM))[lane];
  float4 wa21 = ((const float4*)(wa + FDIM))[lane + 64];
  float s1 = v0.x*wa10.x + v0.y*wa10.y + v0.z*wa10.z + v0.w*wa10.w
           + v1.x*wa11.x + v1.y*wa11.y + v1.z*wa11.z + v1.w*wa11.w;
  float s2 = v0.x*wa20.x + v0.y*wa20.y + v0.z*wa20.z + v0.w*wa20.w
           + v1.x*wa21.x + v1.y*wa21.y + v1.z*wa21.z + v1.w*wa21.w;
  ushort4 u0 = { f2bf(v0.x), f2bf(v0.y), f2bf(v0.z), f2bf(v0.w) };
  ushort4 u1 = { f2bf(v1.x), f2bf(v1.y), f2bf(v1.z), f2bf(v1.w) };
  ushort4* hb = (ushort4*)(Hb + r * FDIM);
  hb[lane] = u0;
  hb[lane + 64] = u1;
  #pragma unroll
  for (int off = 32; off > 0; off >>= 1) {
    s1 += __shfl_down(s1, off);
    s2 += __shfl_down(s2, off);
  }
  if (lane == 0) { Wh1[r] = s1; Wh2[r] = s2; }
}

// ---------------- K2: column sums Z[b,t] AND P = bf16(masked exp) ----------------
__global__ __launch_bounds__(256) void k2_z(const float* __restrict__ adj,
                                            const float* __restrict__ Wh1,
                                            const float* __restrict__ Wh2,
                                            float* __restrict__ Zp,
                                            __hip_bfloat16* __restrict__ P) {
  int t = blockIdx.x * 256 + threadIdx.x;  // grid.x = 8
  int b = blockIdx.y;                      // 8
  int c = blockIdx.z;                      // 32 chunks of 64 s each
  float w2 = Wh2[b * SDIM + t];
  const float* arow = adj + ((long)b * SDIM + c * 64) * SDIM + t;
  const float* w1p = Wh1 + b * SDIM + c * 64;
  __hip_bfloat16* prow = P + ((long)b * SDIM + c * 64) * SDIM + t;
  float z = 0.f;
  #pragma unroll 8
  for (int s = 0; s < 64; ++s) {
    float av = arow[(long)s * SDIM];
    float e = w1p[s] + w2;
    e = fmaxf(e, ALPHA * e);
    float p = (av > 0.5f) ? __expf(e) : 0.f;
    z += p;
    prow[(long)s * SDIM] = __float2bfloat16(p);
  }
  Zp[(b * 32 + c) * SDIM + t] = z;
}

// ---------------- K2b: rZ = 1/sum(partials) ----------------
__global__ void k2b_rz(const float* __restrict__ Zp, float* __restrict__ rZ) {
  int idx = blockIdx.x * 256 + threadIdx.x;  // 16384
  int b = idx >> 11, t = idx & 2047;
  float z = 0.f;
  #pragma unroll
  for (int c = 0; c < 32; ++c) z += Zp[(b * 32 + c) * SDIM + t];
  rZ[idx] = 1.0f / z;
}

// ---------------- K3: V'^T[b][o][t] = bf16( (W^T @ H_b^T)[o][t] * rZ[b,t] ) ----------------
__global__ __launch_bounds__(256) void k3_gemm(const __hip_bfloat16* __restrict__ WTm,
                                               const __hip_bfloat16* __restrict__ Hb,
                                               const float* __restrict__ rZ,
                                               __hip_bfloat16* __restrict__ VT) {
  __shared__ __align__(16) __hip_bfloat16 Asm[2][128 * 32];
  __shared__ __align__(16) __hip_bfloat16 Bsm[2][128 * 32];
  const int o0 = blockIdx.x * 128;
  const int t0 = blockIdx.y * 128;
  const int b = blockIdx.z;
  const int tid = threadIdx.x;
  const int w = tid >> 6, lane = tid & 63;
  const int wm = w >> 1, wn = w & 1;
  const int fr = lane & 15, fq = lane >> 4;
  const int lr = lane >> 2, lb = (lane & 3) * 16;

  const __hip_bfloat16* Abase = WTm + (long)o0 * FDIM;
  const __hip_bfloat16* Bbase = Hb + ((long)b * SDIM + t0) * FDIM;

  f32x4 acc[4][4] = {};

  auto stage = [&](int kk, int buf) {
    #pragma unroll
    for (int g = 0; g < 2; ++g) {
      int rbase = g * 64 + w * 16;
      int row = rbase + lr;
      gload_lds16((const char*)(Abase + (long)row * FDIM + kk * 32) + lb,
                  (char*)&Asm[buf][0] + rbase * 64);
      gload_lds16((const char*)(Bbase + (long)row * FDIM + kk * 32) + lb,
                  (char*)&Bsm[buf][0] + rbase * 64);
    }
  };

  stage(0, 0);
  __syncthreads();
  for (int kk = 0; kk < 16; ++kk) {
    int cur = kk & 1;
    if (kk < 15) stage(kk + 1, cur ^ 1);
    bf16x8 af[4], bf_[4];
    #pragma unroll
    for (int mf = 0; mf < 4; ++mf)
      af[mf] = *(const bf16x8*)((const char*)&Asm[cur][0] + (wm * 64 + mf * 16 + fr) * 64 + fq * 16);
    #pragma unroll
    for (int nf = 0; nf < 4; ++nf)
      bf_[nf] = *(const bf16x8*)((const char*)&Bsm[cur][0] + (wn * 64 + nf * 16 + fr) * 64 + fq * 16);
    #pragma unroll
    for (int mf = 0; mf < 4; ++mf)
      #pragma unroll
      for (int nf = 0; nf < 4; ++nf)
        acc[mf][nf] = __builtin_amdgcn_mfma_f32_16x16x32_bf16(af[mf], bf_[nf], acc[mf][nf], 0, 0, 0);
    __syncthreads();
  }

  #pragma unroll
  for (int nf = 0; nf < 4; ++nf) {
    int t = t0 + wn * 64 + nf * 16 + fr;
    float rz = rZ[b * SDIM + t];
    #pragma unroll
    for (int mf = 0; mf < 4; ++mf) {
      #pragma unroll
      for (int r = 0; r < 4; ++r) {
        int o = o0 + wm * 64 + mf * 16 + fq * 4 + r;
        VT[((long)(b * FDIM + o)) * SDIM + t] = __float2bfloat16(acc[mf][nf][r] * rz);
      }
    }
  }
}

// ---------------- K4 v14: pure staged GEMM, triple-buffer, 2-ahead, vmcnt(5) ----------------
// Per phase per wave exactly 5 vmem (4 stageV + 1 stageP -> buf p+2). At each
// barrier outstanding = stages(p+1)+stages(p+2) = 10; vmcnt(5) retires exactly
// stages(p+1): ~2 phases of latency cover, never drained to 0 until the tail.
__global__ __launch_bounds__(256, 2) void k4_pv(const __hip_bfloat16* __restrict__ P,
                                                const __hip_bfloat16* __restrict__ VT,
                                                float* __restrict__ out) {
  __shared__ __align__(16) __hip_bfloat16 Vsm[3][256 * 32];  // 48 KB
  __shared__ __align__(16) __hip_bfloat16 Psm[3][64 * 32];   // 12 KB
  const int b  = blockIdx.x;        // 8  (linear id % 8 == b -> XCD pinning)
  const int s0 = blockIdx.y * 64;   // 32
  const int ob = blockIdx.z * 256;  // 2
  const int tid = threadIdx.x;
  const int w = tid >> 6, lane = tid & 63;
  const int fr = lane & 15, fq = lane >> 4;
  const int srow = lane >> 2;                        // staging: row within 16-row block
  const int sgam = (lane & 3) ^ ((lane >> 2) & 3);   // staging: XOR'd source granule

  const char* vtG = (const char*)(VT + ((long)(b * FDIM + ob)) * SDIM);
  const char* pG  = (const char*)(P + ((long)(b * SDIM + s0)) * SDIM);

  f32x4 acc[4][4] = {};

  auto stageV = [&](int p, int buf) {
    #pragma unroll
    for (int g = 0; g < 4; ++g) {
      int row = w * 64 + g * 16 + srow;
      gload_lds16(vtG + ((long)row * SDIM + p * 32 + sgam * 8) * 2,
                  (char*)&Vsm[0][0] + buf * 16384 + w * 4096 + g * 1024);
    }
  };
  auto stageP = [&](int p, int buf) {
    int row = w * 16 + srow;
    gload_lds16(pG + ((long)row * SDIM + p * 32 + sgam * 8) * 2,
                (char*)&Psm[0][0] + buf * 4096 + w * 1024);
  };

  // prologue: stages(0)->buf0, stages(1)->buf1; wait stages(0) (vmcnt(5))
  stageV(0, 0); stageP(0, 0);
  stageV(1, 1); stageP(1, 1);
  asm volatile("s_waitcnt vmcnt(5)" ::: "memory");
  __builtin_amdgcn_sched_barrier(0);
  __builtin_amdgcn_s_barrier();

  int bufR = 0;   // buf for phase p
  int bufS = 2;   // stage target = buf for p+2
  for (int p = 0; p < 64; ++p) {
    if (p <= 61) { stageV(p + 2, bufS); stageP(p + 2, bufS); }
    __builtin_amdgcn_sched_barrier(0);        // stages issue at phase top

    bf16x8 pa[4], vb[4];
    #pragma unroll
    for (int mf = 0; mf < 4; ++mf)
      pa[mf] = *(const bf16x8*)((const char*)&Psm[0][0] + bufR * 4096 + mf * 1024
                                + fr * 64 + (fq ^ (fr & 3)) * 16);
    #pragma unroll
    for (int nf = 0; nf < 4; ++nf)
      vb[nf] = *(const bf16x8*)((const char*)&Vsm[0][0] + bufR * 16384 + w * 4096 + nf * 1024
                                + fr * 64 + (fq ^ (fr & 3)) * 16);
    __builtin_amdgcn_s_setprio(1);
    #pragma unroll
    for (int mf = 0; mf < 4; ++mf)
      #pragma unroll
      for (int nf = 0; nf < 4; ++nf)
        acc[mf][nf] = __builtin_amdgcn_mfma_f32_16x16x32_bf16(pa[mf], vb[nf], acc[mf][nf], 0, 0, 0);
    __builtin_amdgcn_s_setprio(0);

    if (p <= 61) { asm volatile("s_waitcnt vmcnt(5)" ::: "memory"); }
    else         { asm volatile("s_waitcnt vmcnt(0)" ::: "memory"); }
    asm volatile("s_waitcnt lgkmcnt(0)" ::: "memory");
    __builtin_amdgcn_sched_barrier(0);
    __builtin_amdgcn_s_barrier();

    bufR = (bufR == 2) ? 0 : bufR + 1;
    bufS = (bufS == 2) ? 0 : bufS + 1;
  }

  // epilogue: ELU + store
  float* orow = out + ((long)b * SDIM + s0) * FDIM + ob + w * 64;
  #pragma unroll
  for (int mf = 0; mf < 4; ++mf) {
    #pragma unroll
    for (int nf = 0; nf < 4; ++nf) {
      #pragma unroll
      for (int r = 0; r < 4; ++r) {
        int s = mf * 16 + fq * 4 + r;
        int o = nf * 16 + fr;
        float x = acc[mf][nf][r];
        x = x > 0.f ? x : (__expf(x) - 1.f);
        orow[(long)s * FDIM + o] = x;
      }
    }
  }
}

extern "C" void kernel_launch(void* const* d_in, const int* in_sizes, int n_in,
                              void* d_out, int out_size, void* d_ws, size_t ws_size,
                              hipStream_t stream) {
  const float* H   = (const float*)d_in[0];   // [8,2048,512]
  const float* adj = (const float*)d_in[1];   // [8,2048,2048]
  const float* W   = (const float*)d_in[2];   // [512,512]
  const float* a   = (const float*)d_in[3];   // [1024,1]
  float* out = (float*)d_out;
  char* ws = (char*)d_ws;

  __hip_bfloat16* VT  = (__hip_bfloat16*)(ws + 0);         // 16 MB  [8][512][2048]
  __hip_bfloat16* Hb  = (__hip_bfloat16*)(ws + 16777216);  // 16 MB  [16384][512]
  __hip_bfloat16* WT  = (__hip_bfloat16*)(ws + 33554432);  // 512 KB [512][512]
  float* wa  = (float*)(ws + 34078720);                    // 4 KB
  float* Wh1 = (float*)(ws + 34082816);                    // 64 KB
  float* Wh2 = (float*)(ws + 34148352);                    // 64 KB
  float* rZ  = (float*)(ws + 34213888);                    // 64 KB
  float* Zp  = (float*)(ws + 34279424);                    // 2 MB
  __hip_bfloat16* P = (__hip_bfloat16*)(ws + 37748736);    // 64 MB  [8][2048][2048]

  hipLaunchKernelGGL(k0_prep, dim3(512), dim3(64), 0, stream, W, a, wa, WT);
  hipLaunchKernelGGL(k1_rows, dim3(4096), dim3(256), 0, stream, H, wa, Wh1, Wh2, Hb);
  hipLaunchKernelGGL(k2_z, dim3(8, 8, 32), dim3(256), 0, stream, adj, Wh1, Wh2, Zp, P);
  hipLaunchKernelGGL(k2b_rz, dim3(64), dim3(256), 0, stream, Zp, rZ);
  hipLaunchKernelGGL(k3_gemm, dim3(4, 16, 8), dim3(256), 0, stream, WT, Hb, rZ, VT);
  hipLaunchKernelGGL(k4_pv, dim3(8, 32, 2), dim3(256), 0, stream, P, VT, out);
}

// Round 15
// 120.468 us; speedup vs baseline: 1.0376x; 1.0277x over previous
//
#include <hip/hip_runtime.h>
#include <hip/hip_bf16.h>
#include <stdint.h>

#define SDIM 2048
#define BDIM 8
#define FDIM 512
constexpr float ALPHA = 0.2f;

typedef __attribute__((ext_vector_type(8))) short bf16x8;
typedef __attribute__((ext_vector_type(4))) float f32x4;

__device__ __forceinline__ unsigned short f2bf(float x) {
  __hip_bfloat16 h = __float2bfloat16(x);
  return *reinterpret_cast<unsigned short*>(&h);
}

__device__ __forceinline__ void gload_lds16(const void* g, void* l) {
  __builtin_amdgcn_global_load_lds(
      (const __attribute__((address_space(1))) unsigned int*)(uintptr_t)g,
      (__attribute__((address_space(3))) unsigned int*)(uintptr_t)l,
      16, 0, 0);
}

// ---------------- K0: wa1/wa2 = W @ a halves (fp32), WT = bf16(W^T) ----------------
__global__ void k0_prep(const float* __restrict__ W, const float* __restrict__ a,
                        float* __restrict__ wa, __hip_bfloat16* __restrict__ WT) {
  int i = blockIdx.x;            // 512 rows of W
  int lane = threadIdx.x;        // 64
  float s1 = 0.f, s2 = 0.f;
  for (int o = lane; o < FDIM; o += 64) {
    float w = W[i * FDIM + o];
    s1 += w * a[o];
    s2 += w * a[FDIM + o];
    WT[o * FDIM + i] = __float2bfloat16(w);
  }
  #pragma unroll
  for (int off = 32; off > 0; off >>= 1) {
    s1 += __shfl_down(s1, off);
    s2 += __shfl_down(s2, off);
  }
  if (lane == 0) { wa[i] = s1; wa[FDIM + i] = s2; }
}

// ---------------- K1: per-row Wh1/Wh2 (fp32) + H -> bf16 ----------------
__global__ __launch_bounds__(256) void k1_rows(const float* __restrict__ H,
                                               const float* __restrict__ wa,
                                               float* __restrict__ Wh1, float* __restrict__ Wh2,
                                               __hip_bfloat16* __restrict__ Hb) {
  int wid = threadIdx.x >> 6, lane = threadIdx.x & 63;
  long r = (long)blockIdx.x * 4 + wid;          // 0..16383
  const float* hr = H + r * FDIM;
  float4 v0 = ((const float4*)hr)[lane];
  float4 v1 = ((const float4*)hr)[lane + 64];
  float4 wa10 = ((const float4*)wa)[lane];
  float4 wa11 = ((const float4*)wa)[lane + 64];
  float4 wa20 = ((const float4*)(wa + FDIM))[lane];
  float4 wa21 = ((const float4*)(wa + FDIM))[lane + 64];
  float s1 = v0.x*wa10.x + v0.y*wa10.y + v0.z*wa10.z + v0.w*wa10.w
           + v1.x*wa11.x + v1.y*wa11.y + v1.z*wa11.z + v1.w*wa11.w;
  float s2 = v0.x*wa20.x + v0.y*wa20.y + v0.z*wa20.z + v0.w*wa20.w
           + v1.x*wa21.x + v1.y*wa21.y + v1.z*wa21.z + v1.w*wa21.w;
  ushort4 u0 = { f2bf(v0.x), f2bf(v0.y), f2bf(v0.z), f2bf(v0.w) };
  ushort4 u1 = { f2bf(v1.x), f2bf(v1.y), f2bf(v1.z), f2bf(v1.w) };
  ushort4* hb = (ushort4*)(Hb + r * FDIM);
  hb[lane] = u0;
  hb[lane + 64] = u1;
  #pragma unroll
  for (int off = 32; off > 0; off >>= 1) {
    s1 += __shfl_down(s1, off);
    s2 += __shfl_down(s2, off);
  }
  if (lane == 0) { Wh1[r] = s1; Wh2[r] = s2; }
}

// ---------------- K2: column sums Z[b,t] AND P = bf16(masked exp) ----------------
__global__ __launch_bounds__(256) void k2_z(const float* __restrict__ adj,
                                            const float* __restrict__ Wh1,
                                            const float* __restrict__ Wh2,
                                            float* __restrict__ Zp,
                                            __hip_bfloat16* __restrict__ P) {
  int t = blockIdx.x * 256 + threadIdx.x;  // grid.x = 8
  int b = blockIdx.y;                      // 8
  int c = blockIdx.z;                      // 32 chunks of 64 s each
  float w2 = Wh2[b * SDIM + t];
  const float* arow = adj + ((long)b * SDIM + c * 64) * SDIM + t;
  const float* w1p = Wh1 + b * SDIM + c * 64;
  __hip_bfloat16* prow = P + ((long)b * SDIM + c * 64) * SDIM + t;
  float z = 0.f;
  #pragma unroll 8
  for (int s = 0; s < 64; ++s) {
    float av = arow[(long)s * SDIM];
    float e = w1p[s] + w2;
    e = fmaxf(e, ALPHA * e);
    float p = (av > 0.5f) ? __expf(e) : 0.f;
    z += p;
    prow[(long)s * SDIM] = __float2bfloat16(p);
  }
  Zp[(b * 32 + c) * SDIM + t] = z;
}

// ---------------- K3: V'^T = bf16( (W^T @ H_b^T) * rZ ), rZ computed inline ----------------
__global__ __launch_bounds__(256) void k3_gemm(const __hip_bfloat16* __restrict__ WTm,
                                               const __hip_bfloat16* __restrict__ Hb,
                                               const float* __restrict__ Zp,
                                               __hip_bfloat16* __restrict__ VT) {
  __shared__ __align__(16) __hip_bfloat16 Asm[2][128 * 32];
  __shared__ __align__(16) __hip_bfloat16 Bsm[2][128 * 32];
  __shared__ float ztmp[256];
  __shared__ float rzLds[128];
  const int o0 = blockIdx.x * 128;
  const int t0 = blockIdx.y * 128;
  const int b = blockIdx.z;
  const int tid = threadIdx.x;
  const int w = tid >> 6, lane = tid & 63;
  const int wm = w >> 1, wn = w & 1;
  const int fr = lane & 15, fq = lane >> 4;
  const int lr = lane >> 2, lb = (lane & 3) * 16;

  const __hip_bfloat16* Abase = WTm + (long)o0 * FDIM;
  const __hip_bfloat16* Bbase = Hb + ((long)b * SDIM + t0) * FDIM;

  f32x4 acc[4][4] = {};

  auto stage = [&](int kk, int buf) {
    #pragma unroll
    for (int g = 0; g < 2; ++g) {
      int rbase = g * 64 + w * 16;
      int row = rbase + lr;
      gload_lds16((const char*)(Abase + (long)row * FDIM + kk * 32) + lb,
                  (char*)&Asm[buf][0] + rbase * 64);
      gload_lds16((const char*)(Bbase + (long)row * FDIM + kk * 32) + lb,
                  (char*)&Bsm[buf][0] + rbase * 64);
    }
  };

  stage(0, 0);
  // rZ prologue (folded k2b): thread (tl,h) sums 16 Zp partials for col t0+tl
  {
    int tl = tid & 127, h = tid >> 7;
    int t = t0 + tl;
    float z = 0.f;
    #pragma unroll
    for (int c = 0; c < 16; ++c)
      z += Zp[((b * 32) + h * 16 + c) * SDIM + t];
    ztmp[tid] = z;
  }
  __syncthreads();
  if (tid < 128) rzLds[tid] = 1.0f / (ztmp[tid] + ztmp[tid + 128]);
  __syncthreads();

  for (int kk = 0; kk < 16; ++kk) {
    int cur = kk & 1;
    if (kk < 15) stage(kk + 1, cur ^ 1);
    bf16x8 af[4], bf_[4];
    #pragma unroll
    for (int mf = 0; mf < 4; ++mf)
      af[mf] = *(const bf16x8*)((const char*)&Asm[cur][0] + (wm * 64 + mf * 16 + fr) * 64 + fq * 16);
    #pragma unroll
    for (int nf = 0; nf < 4; ++nf)
      bf_[nf] = *(const bf16x8*)((const char*)&Bsm[cur][0] + (wn * 64 + nf * 16 + fr) * 64 + fq * 16);
    #pragma unroll
    for (int mf = 0; mf < 4; ++mf)
      #pragma unroll
      for (int nf = 0; nf < 4; ++nf)
        acc[mf][nf] = __builtin_amdgcn_mfma_f32_16x16x32_bf16(af[mf], bf_[nf], acc[mf][nf], 0, 0, 0);
    __syncthreads();
  }

  #pragma unroll
  for (int nf = 0; nf < 4; ++nf) {
    int tl = wn * 64 + nf * 16 + fr;
    int t = t0 + tl;
    float rz = rzLds[tl];
    #pragma unroll
    for (int mf = 0; mf < 4; ++mf) {
      #pragma unroll
      for (int r = 0; r < 4; ++r) {
        int o = o0 + wm * 64 + mf * 16 + fq * 4 + r;
        VT[((long)(b * FDIM + o)) * SDIM + t] = __float2bfloat16(acc[mf][nf][r] * rz);
      }
    }
  }
}

// ---------------- K4 v14: pure staged GEMM, triple-buffer, 2-ahead, vmcnt(5) ----------------
__global__ __launch_bounds__(256, 2) void k4_pv(const __hip_bfloat16* __restrict__ P,
                                                const __hip_bfloat16* __restrict__ VT,
                                                float* __restrict__ out) {
  __shared__ __align__(16) __hip_bfloat16 Vsm[3][256 * 32];  // 48 KB
  __shared__ __align__(16) __hip_bfloat16 Psm[3][64 * 32];   // 12 KB
  const int b  = blockIdx.x;        // 8  (linear id % 8 == b -> XCD pinning)
  const int s0 = blockIdx.y * 64;   // 32
  const int ob = blockIdx.z * 256;  // 2
  const int tid = threadIdx.x;
  const int w = tid >> 6, lane = tid & 63;
  const int fr = lane & 15, fq = lane >> 4;
  const int srow = lane >> 2;                        // staging: row within 16-row block
  const int sgam = (lane & 3) ^ ((lane >> 2) & 3);   // staging: XOR'd source granule

  const char* vtG = (const char*)(VT + ((long)(b * FDIM + ob)) * SDIM);
  const char* pG  = (const char*)(P + ((long)(b * SDIM + s0)) * SDIM);

  f32x4 acc[4][4] = {};

  auto stageV = [&](int p, int buf) {
    #pragma unroll
    for (int g = 0; g < 4; ++g) {
      int row = w * 64 + g * 16 + srow;
      gload_lds16(vtG + ((long)row * SDIM + p * 32 + sgam * 8) * 2,
                  (char*)&Vsm[0][0] + buf * 16384 + w * 4096 + g * 1024);
    }
  };
  auto stageP = [&](int p, int buf) {
    int row = w * 16 + srow;
    gload_lds16(pG + ((long)row * SDIM + p * 32 + sgam * 8) * 2,
                (char*)&Psm[0][0] + buf * 4096 + w * 1024);
  };

  // prologue: stages(0)->buf0, stages(1)->buf1; wait stages(0) (vmcnt(5))
  stageV(0, 0); stageP(0, 0);
  stageV(1, 1); stageP(1, 1);
  asm volatile("s_waitcnt vmcnt(5)" ::: "memory");
  __builtin_amdgcn_sched_barrier(0);
  __builtin_amdgcn_s_barrier();

  int bufR = 0;   // buf for phase p
  int bufS = 2;   // stage target = buf for p+2
  for (int p = 0; p < 64; ++p) {
    if (p <= 61) { stageV(p + 2, bufS); stageP(p + 2, bufS); }
    __builtin_amdgcn_sched_barrier(0);        // stages issue at phase top

    bf16x8 pa[4], vb[4];
    #pragma unroll
    for (int mf = 0; mf < 4; ++mf)
      pa[mf] = *(const bf16x8*)((const char*)&Psm[0][0] + bufR * 4096 + mf * 1024
                                + fr * 64 + (fq ^ (fr & 3)) * 16);
    #pragma unroll
    for (int nf = 0; nf < 4; ++nf)
      vb[nf] = *(const bf16x8*)((const char*)&Vsm[0][0] + bufR * 16384 + w * 4096 + nf * 1024
                                + fr * 64 + (fq ^ (fr & 3)) * 16);
    __builtin_amdgcn_s_setprio(1);
    #pragma unroll
    for (int mf = 0; mf < 4; ++mf)
      #pragma unroll
      for (int nf = 0; nf < 4; ++nf)
        acc[mf][nf] = __builtin_amdgcn_mfma_f32_16x16x32_bf16(pa[mf], vb[nf], acc[mf][nf], 0, 0, 0);
    __builtin_amdgcn_s_setprio(0);

    if (p <= 61) { asm volatile("s_waitcnt vmcnt(5)" ::: "memory"); }
    else         { asm volatile("s_waitcnt vmcnt(0)" ::: "memory"); }
    asm volatile("s_waitcnt lgkmcnt(0)" ::: "memory");
    __builtin_amdgcn_sched_barrier(0);
    __builtin_amdgcn_s_barrier();

    bufR = (bufR == 2) ? 0 : bufR + 1;
    bufS = (bufS == 2) ? 0 : bufS + 1;
  }

  // epilogue: ELU + store
  float* orow = out + ((long)b * SDIM + s0) * FDIM + ob + w * 64;
  #pragma unroll
  for (int mf = 0; mf < 4; ++mf) {
    #pragma unroll
    for (int nf = 0; nf < 4; ++nf) {
      #pragma unroll
      for (int r = 0; r < 4; ++r) {
        int s = mf * 16 + fq * 4 + r;
        int o = nf * 16 + fr;
        float x = acc[mf][nf][r];
        x = x > 0.f ? x : (__expf(x) - 1.f);
        orow[(long)s * FDIM + o] = x;
      }
    }
  }
}

extern "C" void kernel_launch(void* const* d_in, const int* in_sizes, int n_in,
                              void* d_out, int out_size, void* d_ws, size_t ws_size,
                              hipStream_t stream) {
  const float* H   = (const float*)d_in[0];   // [8,2048,512]
  const float* adj = (const float*)d_in[1];   // [8,2048,2048]
  const float* W   = (const float*)d_in[2];   // [512,512]
  const float* a   = (const float*)d_in[3];   // [1024,1]
  float* out = (float*)d_out;
  char* ws = (char*)d_ws;

  __hip_bfloat16* VT  = (__hip_bfloat16*)(ws + 0);         // 16 MB  [8][512][2048]
  __hip_bfloat16* Hb  = (__hip_bfloat16*)(ws + 16777216);  // 16 MB  [16384][512]
  __hip_bfloat16* WT  = (__hip_bfloat16*)(ws + 33554432);  // 512 KB [512][512]
  float* wa  = (float*)(ws + 34078720);                    // 4 KB
  float* Wh1 = (float*)(ws + 34082816);                    // 64 KB
  float* Wh2 = (float*)(ws + 34148352);                    // 64 KB
  float* Zp  = (float*)(ws + 34279424);                    // 2 MB
  __hip_bfloat16* P = (__hip_bfloat16*)(ws + 37748736);    // 64 MB  [8][2048][2048]

  hipLaunchKernelGGL(k0_prep, dim3(512), dim3(64), 0, stream, W, a, wa, WT);
  hipLaunchKernelGGL(k1_rows, dim3(4096), dim3(256), 0, stream, H, wa, Wh1, Wh2, Hb);
  hipLaunchKernelGGL(k2_z, dim3(8, 8, 32), dim3(256), 0, stream, adj, Wh1, Wh2, Zp, P);
  hipLaunchKernelGGL(k3_gemm, dim3(4, 16, 8), dim3(256), 0, stream, WT, Hb, Zp, VT);
  hipLaunchKernelGGL(k4_pv, dim3(8, 32, 2), dim3(256), 0, stream, P, VT, out);
}